// Round 5
// baseline (1003.480 us; speedup 1.0000x reference)
//
#include <hip/hip_runtime.h>
#include <math.h>

// Problem constants: B=8, Tt=16, C=1, H=W=512, 4 in-channels, 10 T-planes.
#define Bd 8
#define Td 16
#define Hd 512
#define Wd 512
#define HWc (Hd * Wd)          // 262144
#define NPIX (Bd * HWc)        // 2,097,152

// Fused-step tiling: 64x64 output tile, halo 6, T in registers, 1x8 strips.
#define TS   64
#define H6   6
#define RS   76                // TS + 2*H6
#define RR   78                // LDS rows: 1 guard + 76 + 1 guard
#define LP   92                // LDS row pitch in words (16B-aligned, bank spread)
#define NTHR 768               // 76 rows * 10 strips = 760 active
#define NSTRIP 10

// ---------------------------------------------------------------------------
// Kernel 1: T = conv2d(x[:, -4:, 0], W_unet, SAME) + b_unet, fused with
// xt0 = stencil(x[:,15,0], T) -> out[:, 0]   (x15 == input channel 3).
// T layout: (B, 10, 512, 512) plane-major in workspace.
// ---------------------------------------------------------------------------
__global__ void conv_step0_kernel(const float* __restrict__ x,
                                  const float* __restrict__ Wu,
                                  const float* __restrict__ bu,
                                  float* __restrict__ T,
                                  float* __restrict__ out) {
    __shared__ float sW[370];
    for (int idx = threadIdx.x; idx < 370; idx += blockDim.x)
        sW[idx] = (idx < 360) ? Wu[idx] : bu[idx - 360];
    __syncthreads();

    int n = blockIdx.x * blockDim.x + threadIdx.x;
    if (n >= NPIX) return;
    int b   = n >> 18;
    int rem = n & (HWc - 1);
    int i   = rem >> 9;
    int j   = rem & (Wd - 1);

    const float* xb = x + ((size_t)b * Td + 12) * HWc;
    float xv[4][3][3];
    #pragma unroll
    for (int c = 0; c < 4; ++c)
        #pragma unroll
        for (int kh = 0; kh < 3; ++kh) {
            int ii = i + kh - 1;
            bool iv = (ii >= 0) && (ii < Hd);
            #pragma unroll
            for (int kw = 0; kw < 3; ++kw) {
                int jj = j + kw - 1;
                bool jv = (jj >= 0) && (jj < Wd);
                xv[c][kh][kw] = (iv && jv) ? xb[(size_t)c * HWc + ii * Wd + jj] : 0.0f;
            }
        }

    float tacc[10];
    float* Tb = T + (size_t)b * 10 * HWc + rem;
    #pragma unroll
    for (int o = 0; o < 10; ++o) {
        float acc = sW[360 + o];
        #pragma unroll
        for (int c = 0; c < 4; ++c)
            #pragma unroll
            for (int kh = 0; kh < 3; ++kh)
                #pragma unroll
                for (int kw = 0; kw < 3; ++kw)
                    acc += xv[c][kh][kw] * sW[((o * 4 + c) * 3 + kh) * 3 + kw];
        tacc[o] = acc;
        Tb[(size_t)o * HWc] = acc;
    }

    // xt0: k = dj*3+di multiplies x15[i+di-1, j+dj-1]; xv[3] is slice 15.
    float o0 = tacc[9];
    #pragma unroll
    for (int dj = 0; dj < 3; ++dj)
        #pragma unroll
        for (int di = 0; di < 3; ++di)
            o0 += xv[3][di][dj] * tacc[dj * 3 + di];
    out[(size_t)b * Td * HWc + rem] = o0;
}

// ---------------------------------------------------------------------------
// Kernel 2: one scan-body iteration = 6 fused stencil steps.
// T held in registers (10 coefs x 8-pixel strip), x ping-pong in LDS with
// b128 strip reads/writes. Sigmoid at even sub-steps. Region ring is never
// written (stale), contamination moves <=1 px/step, halo 6 keeps core clean.
// LDS layout: [RR=78 rows][LP=92 words]; data col c -> word c+4 (left guard
// for b128 alignment only -- guard values never feed FMAs), data row r ->
// LDS row r+1.
// ---------------------------------------------------------------------------
__global__ __launch_bounds__(NTHR, 3)
void fused6_strip_kernel(const float* __restrict__ xin,   // out slot t-1 base
                         const float* __restrict__ T,
                         float* __restrict__ xout) {      // out slot t base
    __shared__ __align__(16) float sA[RR * LP];
    __shared__ __align__(16) float sB[RR * LP];

    int tile = blockIdx.x;          // 512 = 8 batches * 8x8 tiles
    int b  = tile >> 6;
    int trr = (tile >> 3) & 7;
    int tcc = tile & 7;
    int ri = trr * TS - H6;
    int rj = tcc * TS - H6;

    const float* xb = xin + (size_t)b * Td * HWc;
    const float* Tb = T + (size_t)b * 10 * HWc;
    int tid = threadIdx.x;

    // Stage sA (zeros outside image), zero sB.
    for (int idx = tid; idx < RR * LP; idx += NTHR) {
        int rr = idx / LP, cc = idx - rr * LP;
        int gi = ri + rr - 1, gj = rj + cc - 4;
        float v = 0.0f;
        if (rr >= 1 && rr <= RS && cc >= 4 && cc < 4 + RS &&
            (unsigned)gi < (unsigned)Hd && (unsigned)gj < (unsigned)Wd)
            v = xb[gi * Wd + gj];
        sA[idx] = v;
        sB[idx] = 0.0f;
    }

    bool active = tid < RS * NSTRIP;          // 760
    int r  = tid / NSTRIP;                    // region row 0..75
    int sb = tid - r * NSTRIP;                // strip 0..9
    if (!active) { r = 0; sb = 0; }
    int gi0 = ri + r;
    int gj0 = rj + sb * 8;

    // Per-pixel masks: imask = inside image; wmask = writable interior.
    unsigned imask = 0, wmask = 0;
    #pragma unroll
    for (int p = 0; p < 8; ++p) {
        int c  = sb * 8 + p;                  // data col 0..79 (76..79 = pad)
        int gj = gj0 + p;
        bool im = active && ((unsigned)gi0 < (unsigned)Hd) && ((unsigned)gj < (unsigned)Wd);
        bool wr = active && (r >= 1) && (r <= RS - 2) && (c >= 1) && (c <= RS - 2);
        if (im) imask |= (1u << p);
        if (wr) wmask |= (1u << p);
    }

    // T coefficients for the strip (only threads that compute).
    float tg[10][8];
    if (wmask) {
        bool fullin = ((unsigned)gi0 < (unsigned)Hd) && (gj0 >= 0) && (gj0 + 7 < Wd);
        if (fullin) {
            #pragma unroll
            for (int k = 0; k < 10; ++k) {
                const float4* tp = (const float4*)(Tb + (size_t)k * HWc + gi0 * Wd + gj0);
                float4 a = tp[0], bq = tp[1];
                tg[k][0] = a.x;  tg[k][1] = a.y;  tg[k][2] = a.z;  tg[k][3] = a.w;
                tg[k][4] = bq.x; tg[k][5] = bq.y; tg[k][6] = bq.z; tg[k][7] = bq.w;
            }
        } else {
            #pragma unroll
            for (int k = 0; k < 10; ++k)
                #pragma unroll
                for (int p = 0; p < 8; ++p)
                    tg[k][p] = ((imask >> p) & 1u)
                             ? Tb[(size_t)k * HWc + gi0 * Wd + (gj0 + p)] : 0.0f;
        }
    }
    __syncthreads();

    float* cur = sA;
    float* nxt = sB;

    #pragma unroll
    for (int s = 1; s <= 6; ++s) {
        if (wmask) {
            // Load 3 rows x 16 words (b128 x4 per row). Needed data cols are
            // [8sb-1, 8sb+8] -> loaded indices 3..12.
            float rowv[3][16];
            #pragma unroll
            for (int dr = 0; dr < 3; ++dr) {
                const float4* rp = (const float4*)&cur[(r + dr) * LP + sb * 8];
                float4 q0 = rp[0], q1 = rp[1], q2 = rp[2], q3 = rp[3];
                rowv[dr][0]=q0.x; rowv[dr][1]=q0.y; rowv[dr][2]=q0.z; rowv[dr][3]=q0.w;
                rowv[dr][4]=q1.x; rowv[dr][5]=q1.y; rowv[dr][6]=q1.z; rowv[dr][7]=q1.w;
                rowv[dr][8]=q2.x; rowv[dr][9]=q2.y; rowv[dr][10]=q2.z; rowv[dr][11]=q2.w;
                rowv[dr][12]=q3.x; rowv[dr][13]=q3.y; rowv[dr][14]=q3.z; rowv[dr][15]=q3.w;
            }

            float acc[8];
            #pragma unroll
            for (int p = 0; p < 8; ++p) {
                float a = tg[9][p];
                #pragma unroll
                for (int dj = 0; dj < 3; ++dj)
                    #pragma unroll
                    for (int di = 0; di < 3; ++di)
                        a += rowv[di][p + 3 + dj] * tg[dj * 3 + di][p];
                if ((s & 1) == 0) a = 1.0f / (1.0f + __expf(-a));
                acc[p] = ((imask >> p) & 1u) ? a : 0.0f;
            }

            int wb = (r + 1) * LP + sb * 8 + 4;   // 16B-aligned
            if ((wmask & 0x0Fu) == 0x0Fu) {
                float4 lo = {acc[0], acc[1], acc[2], acc[3]};
                *(float4*)&nxt[wb] = lo;
            } else {
                if (wmask & 0x01u) nxt[wb + 0] = acc[0];
                if (wmask & 0x02u) nxt[wb + 1] = acc[1];
                if (wmask & 0x04u) nxt[wb + 2] = acc[2];
                if (wmask & 0x08u) nxt[wb + 3] = acc[3];
            }
            if ((wmask & 0xF0u) == 0xF0u) {
                float4 hi = {acc[4], acc[5], acc[6], acc[7]};
                *(float4*)&nxt[wb + 4] = hi;
            } else {
                if (wmask & 0x10u) nxt[wb + 4] = acc[4];
                if (wmask & 0x20u) nxt[wb + 5] = acc[5];
                if (wmask & 0x40u) nxt[wb + 6] = acc[6];
                if (wmask & 0x80u) nxt[wb + 7] = acc[7];
            }
        }
        __syncthreads();
        float* tmp = cur; cur = nxt; nxt = tmp;
    }

    // After 6 swaps the result is back in sA (== cur). Write 64x64 core.
    float* ob = xout + (size_t)b * Td * HWc;
    for (int idx = tid; idx < TS * TS; idx += NTHR) {
        int rr2 = idx >> 6, cc2 = idx & 63;
        ob[(ri + H6 + rr2) * Wd + (rj + H6 + cc2)] =
            cur[(H6 + rr2 + 1) * LP + (H6 + cc2 + 4)];
    }
}

// ---------------------------------------------------------------------------
// Workspace: T only (B*10*H*W fp32 = 80 MB).
// ---------------------------------------------------------------------------
extern "C" void kernel_launch(void* const* d_in, const int* in_sizes, int n_in,
                              void* d_out, int out_size, void* d_ws, size_t ws_size,
                              hipStream_t stream) {
    const float* x  = (const float*)d_in[0];
    const float* Wu = (const float*)d_in[1];
    const float* bu = (const float*)d_in[2];
    float* out = (float*)d_out;
    float* T   = (float*)d_ws;

    conv_step0_kernel<<<NPIX / 256, 256, 0, stream>>>(x, Wu, bu, T, out);

    for (int t = 1; t < Td; ++t)
        fused6_strip_kernel<<<512, NTHR, 0, stream>>>(out + (size_t)(t - 1) * HWc, T,
                                                      out + (size_t)t * HWc);
}

// Round 6
// 624.925 us; speedup vs baseline: 1.6058x; 1.6058x over previous
//
#include <hip/hip_runtime.h>
#include <hip/hip_fp16.h>
#include <math.h>

// Problem constants: B=8, Tt=16, C=1, H=W=512, 4 in-channels, 10 T-planes.
#define Bd 8
#define Td 16
#define Hd 512
#define Wd 512
#define HWc (Hd * Wd)          // 262144
#define NPIX (Bd * HWc)        // 2,097,152

// Fused-step tiling: 64x64 output tile, halo 6, T(fp16) in registers,
// vertical 8-row strips per thread, x ping-pong in LDS.
#define TS   64
#define H6   6
#define RS   76                // TS + 2*H6
#define LP   77                // LDS row pitch (bank spread)
#define NTHR 768
#define RPG  8                 // owned rows per thread
#define NG   10                // groups: ceil(74 interior rows / 8)

// ---------------------------------------------------------------------------
// Kernel 1: T = conv2d(x[:, -4:, 0], W_unet, SAME) + b_unet, fused with
// xt0 = stencil(x[:,15,0], T) -> out[:, 0].
// T stored as half2 pairs: plane q holds (T[2q], T[2q+1]); layout (B,5,H,W).
// ---------------------------------------------------------------------------
__global__ void conv_step0_kernel(const float* __restrict__ x,
                                  const float* __restrict__ Wu,
                                  const float* __restrict__ bu,
                                  __half2* __restrict__ T,
                                  float* __restrict__ out) {
    __shared__ float sW[370];
    for (int idx = threadIdx.x; idx < 370; idx += blockDim.x)
        sW[idx] = (idx < 360) ? Wu[idx] : bu[idx - 360];
    __syncthreads();

    int n = blockIdx.x * blockDim.x + threadIdx.x;
    if (n >= NPIX) return;
    int b   = n >> 18;
    int rem = n & (HWc - 1);
    int i   = rem >> 9;
    int j   = rem & (Wd - 1);

    const float* xb = x + ((size_t)b * Td + 12) * HWc;
    float xv[4][3][3];
    #pragma unroll
    for (int c = 0; c < 4; ++c)
        #pragma unroll
        for (int kh = 0; kh < 3; ++kh) {
            int ii = i + kh - 1;
            bool iv = (ii >= 0) && (ii < Hd);
            #pragma unroll
            for (int kw = 0; kw < 3; ++kw) {
                int jj = j + kw - 1;
                bool jv = (jj >= 0) && (jj < Wd);
                xv[c][kh][kw] = (iv && jv) ? xb[(size_t)c * HWc + ii * Wd + jj] : 0.0f;
            }
        }

    float tacc[10];
    #pragma unroll
    for (int o = 0; o < 10; ++o) {
        float acc = sW[360 + o];
        #pragma unroll
        for (int c = 0; c < 4; ++c)
            #pragma unroll
            for (int kh = 0; kh < 3; ++kh)
                #pragma unroll
                for (int kw = 0; kw < 3; ++kw)
                    acc += xv[c][kh][kw] * sW[((o * 4 + c) * 3 + kh) * 3 + kw];
        tacc[o] = acc;
    }

    __half2* Tb = T + (size_t)b * 5 * HWc + rem;
    #pragma unroll
    for (int q = 0; q < 5; ++q)
        Tb[(size_t)q * HWc] = __floats2half2_rn(tacc[2 * q], tacc[2 * q + 1]);

    // xt0: k = dj*3+di multiplies x15[i+di-1, j+dj-1]; xv[3] is slice 15.
    // Use fp32 tacc directly (exact vs reference conv; fp16 only affects T reuse).
    float o0 = tacc[9];
    #pragma unroll
    for (int dj = 0; dj < 3; ++dj)
        #pragma unroll
        for (int di = 0; di < 3; ++di)
            o0 += xv[3][di][dj] * tacc[dj * 3 + di];
    out[(size_t)b * Td * HWc + rem] = o0;
}

// ---------------------------------------------------------------------------
// Kernel 2: one scan-body iteration = 6 fused stencil steps.
// Thread t owns column c = t%76, rows rs..rs+7 (rs = 1 + 8*(t/76)); its 40
// fp16 T coefs live in 40 VGPRs; x ping-pongs in LDS with a streaming
// 3x3 window (3 new ds_reads per owned row). Sigmoid at even sub-steps.
// Region ring never written; contamination <=1 px/step; halo 6 protects core.
// ---------------------------------------------------------------------------
__global__ __launch_bounds__(NTHR, 6)
void fused6_vstrip_kernel(const float* __restrict__ xin,   // out slot t-1 base
                          const __half2* __restrict__ T,
                          float* __restrict__ xout) {      // out slot t base
    __shared__ float sA[RS * LP];
    __shared__ float sB[RS * LP];

    int tile = blockIdx.x;          // 512 = 8 batches * 8x8 tiles
    int b   = tile >> 6;
    int trr = (tile >> 3) & 7;
    int tcc = tile & 7;
    int ri = trr * TS - H6;
    int rj = tcc * TS - H6;

    const float* xb = xin + (size_t)b * Td * HWc;
    const __half2* Tb = T + (size_t)b * 5 * HWc;
    int tid = threadIdx.x;

    // Stage sA (zeros outside image), zero sB.
    for (int idx = tid; idx < RS * RS; idx += NTHR) {
        int r = idx / RS, c = idx - r * RS;
        int gi = ri + r, gj = rj + c;
        float v = 0.0f;
        if ((unsigned)gi < (unsigned)Hd && (unsigned)gj < (unsigned)Wd)
            v = xb[gi * Wd + gj];
        sA[r * LP + c] = v;
        sB[r * LP + c] = 0.0f;
    }

    int g  = tid / RS;              // row group 0..9 valid
    int c  = tid - g * RS;          // column 0..75
    int rs = 1 + g * RPG;           // first owned row
    bool colint = (c >= 1) && (c <= RS - 2);
    bool active = (g < NG) && colint;
    int  gj     = rj + c;
    bool colin  = (unsigned)gj < (unsigned)Wd;

    // T coefficients: 5 half2 per owned row.
    __half2 treg[RPG][5];
    #pragma unroll
    for (int jj = 0; jj < RPG; ++jj) {
        int r  = rs + jj;
        int gi = ri + r;
        bool ok = active && (r <= RS - 2) && ((unsigned)gi < (unsigned)Hd) && colin;
        #pragma unroll
        for (int q = 0; q < 5; ++q)
            treg[jj][q] = ok ? Tb[(size_t)q * HWc + gi * Wd + gj]
                             : __floats2half2_rn(0.0f, 0.0f);
    }
    __syncthreads();

    float* cur = sA;
    float* nxt = sB;

    #pragma unroll
    for (int s = 1; s <= 6; ++s) {
        if (active) {
            // Streaming 3-column window over rows rs-1 .. rs+8 (clamped).
            float w00 = cur[(rs - 1) * LP + c - 1];
            float w01 = cur[(rs - 1) * LP + c];
            float w02 = cur[(rs - 1) * LP + c + 1];
            float w10 = cur[rs * LP + c - 1];
            float w11 = cur[rs * LP + c];
            float w12 = cur[rs * LP + c + 1];
            #pragma unroll
            for (int jj = 0; jj < RPG; ++jj) {
                int r  = rs + jj;
                int r2 = (r + 1 <= RS - 1) ? (r + 1) : (RS - 1);  // clamp (g=9 tail)
                float w20 = cur[r2 * LP + c - 1];
                float w21 = cur[r2 * LP + c];
                float w22 = cur[r2 * LP + c + 1];

                float2 p0 = __half22float2(treg[jj][0]);  // T0,T1
                float2 p1 = __half22float2(treg[jj][1]);  // T2,T3
                float2 p2 = __half22float2(treg[jj][2]);  // T4,T5
                float2 p3 = __half22float2(treg[jj][3]);  // T6,T7
                float2 p4 = __half22float2(treg[jj][4]);  // T8,T9

                // k = dj*3+di multiplies x[r+di-1][c+dj-1]
                float a = p4.y
                        + w00 * p0.x + w10 * p0.y + w20 * p1.x
                        + w01 * p1.y + w11 * p2.x + w21 * p2.y
                        + w02 * p3.x + w12 * p3.y + w22 * p4.x;
                if ((s & 1) == 0) a = 1.0f / (1.0f + __expf(-a));

                int gi = ri + r;
                bool rowok = (r <= RS - 2);
                bool inimg = ((unsigned)gi < (unsigned)Hd) && colin;
                if (rowok) nxt[r * LP + c] = inimg ? a : 0.0f;

                w00 = w10; w01 = w11; w02 = w12;
                w10 = w20; w11 = w21; w12 = w22;
            }
        }
        __syncthreads();
        float* tmp = cur; cur = nxt; nxt = tmp;
    }

    // After 6 swaps the result is back in sA (== cur). Write 64x64 core.
    float* ob = xout + (size_t)b * Td * HWc;
    for (int idx = tid; idx < TS * TS; idx += NTHR) {
        int rr = idx >> 6, cc = idx & 63;
        ob[(ri + H6 + rr) * Wd + (rj + H6 + cc)] = cur[(H6 + rr) * LP + (H6 + cc)];
    }
}

// ---------------------------------------------------------------------------
// Workspace: T only (B*5*H*W half2 = 40 MB).
// ---------------------------------------------------------------------------
extern "C" void kernel_launch(void* const* d_in, const int* in_sizes, int n_in,
                              void* d_out, int out_size, void* d_ws, size_t ws_size,
                              hipStream_t stream) {
    const float* x  = (const float*)d_in[0];
    const float* Wu = (const float*)d_in[1];
    const float* bu = (const float*)d_in[2];
    float* out = (float*)d_out;
    __half2* T = (__half2*)d_ws;

    conv_step0_kernel<<<NPIX / 256, 256, 0, stream>>>(x, Wu, bu, T, out);

    for (int t = 1; t < Td; ++t)
        fused6_vstrip_kernel<<<512, NTHR, 0, stream>>>(out + (size_t)(t - 1) * HWc, T,
                                                       out + (size_t)t * HWc);
}

// Round 7
// 572.646 us; speedup vs baseline: 1.7524x; 1.0913x over previous
//
#include <hip/hip_runtime.h>
#include <hip/hip_fp16.h>
#include <math.h>

// Problem constants: B=8, Tt=16, C=1, H=W=512, 4 in-channels, 10 T-planes.
#define Bd 8
#define Td 16
#define Hd 512
#define Wd 512
#define HWc (Hd * Wd)          // 262144
#define NPIX (Bd * HWc)        // 2,097,152

// ---------------- conv tiling: 128x8 tile, 2 px/thread, 512 threads ----------
#define CTW 128                // tile cols
#define CTH 8                  // tile rows
#define CRW 130                // region cols
#define CRH 10                 // region rows
#define CPITCH 132             // LDS row pitch (words)
#define CTHR 512

// ---------------- fused-step tiling (unchanged from round 6) -----------------
#define TS   64
#define H6   6
#define RS   76                // TS + 2*H6
#define LP   77                // LDS row pitch
#define NTHR 768
#define RPG  8                 // owned rows per thread
#define NG   10                // row groups

// ---------------------------------------------------------------------------
// Kernel 1: tiled conv  T = conv2d(x[:, -4:, 0], W_unet, SAME) + b_unet,
// fused with xt0 = stencil(x[:,15,0], T_fp32) -> out[:, 0].
// T stored as half2 pairs: plane q holds (T[2q], T[2q+1]); layout (B,5,H,W).
// Weights/bias read via uniform global indices -> scalar loads (K$), no LDS.
// ---------------------------------------------------------------------------
__global__ __launch_bounds__(CTHR)
void conv_step0_kernel(const float* __restrict__ x,
                       const float* __restrict__ Wu,
                       const float* __restrict__ bu,
                       __half2* __restrict__ T,
                       float* __restrict__ out) {
    __shared__ __align__(16) float sX[4][CRH][CPITCH];   // 21.1 KB

    int bx  = blockIdx.x;           // 2048 = 8 b * 64 row-bands * 4 col-bands
    int b   = bx >> 8;
    int rem = bx & 255;
    int by  = rem >> 2;             // row band 0..63
    int bc  = rem & 3;              // col band 0..3
    int i0  = by * CTH;
    int j0  = bc * CTW;

    const float* xb = x + ((size_t)b * Td + 12) * HWc;   // channel c -> slice 12+c
    int tid = threadIdx.x;

    // Stage the 4-channel 10x130 region (zeros outside image). Coalesced rows.
    for (int idx = tid; idx < 4 * CRH * CRW; idx += CTHR) {
        int ch = idx / (CRH * CRW);
        int r2 = idx - ch * (CRH * CRW);
        int r  = r2 / CRW;
        int c  = r2 - r * CRW;
        int gi = i0 + r - 1, gj = j0 + c - 1;
        float v = 0.0f;
        if ((unsigned)gi < (unsigned)Hd && (unsigned)gj < (unsigned)Wd)
            v = xb[(size_t)ch * HWc + gi * Wd + gj];
        sX[ch][r][c] = v;
    }
    __syncthreads();

    int tx = tid & 63;              // pixel pair: cols 2tx, 2tx+1
    int ty = tid >> 6;              // tile row 0..7

    float t0[10], t1[10];
    #pragma unroll
    for (int o = 0; o < 10; ++o) { float bv = bu[o]; t0[o] = bv; t1[o] = bv; }

    #pragma unroll
    for (int ch = 0; ch < 4; ++ch)
        #pragma unroll
        for (int kh = 0; kh < 3; ++kh) {
            const float* rp = &sX[ch][ty + kh][2 * tx];
            float2 a  = *(const float2*)rp;        // region cols 2tx, 2tx+1
            float2 b2 = *(const float2*)(rp + 2);  // region cols 2tx+2, 2tx+3
            float w0 = a.x, w1 = a.y, w2 = b2.x, w3 = b2.y;
            #pragma unroll
            for (int o = 0; o < 10; ++o) {
                float wt0 = Wu[((o * 4 + ch) * 3 + kh) * 3 + 0];
                float wt1 = Wu[((o * 4 + ch) * 3 + kh) * 3 + 1];
                float wt2 = Wu[((o * 4 + ch) * 3 + kh) * 3 + 2];
                t0[o] += w0 * wt0 + w1 * wt1 + w2 * wt2;
                t1[o] += w1 * wt0 + w2 * wt1 + w3 * wt2;
            }
        }

    int gi = i0 + ty;
    int gjv = j0 + 2 * tx;
    size_t pix = (size_t)gi * Wd + gjv;            // even
    __half2* Tb = T + (size_t)b * 5 * HWc;
    #pragma unroll
    for (int q = 0; q < 5; ++q) {
        __half2 h0 = __floats2half2_rn(t0[2 * q], t0[2 * q + 1]);
        __half2 h1 = __floats2half2_rn(t1[2 * q], t1[2 * q + 1]);
        uint2 pk;
        pk.x = *(unsigned*)&h0;
        pk.y = *(unsigned*)&h1;
        *(uint2*)(Tb + (size_t)q * HWc + pix) = pk;
    }

    // step0 on channel 3 (slice 15), fp32 coefficients (exact structure).
    // k = dj*3+di multiplies x15[i+di-1, j+dj-1].
    float o0 = t0[9], o1 = t1[9];
    #pragma unroll
    for (int di = 0; di < 3; ++di) {
        const float* rp = &sX[3][ty + di][2 * tx];
        float2 a  = *(const float2*)rp;
        float2 b2 = *(const float2*)(rp + 2);
        float w0 = a.x, w1 = a.y, w2 = b2.x, w3 = b2.y;
        #pragma unroll
        for (int dj = 0; dj < 3; ++dj) {
            float xa = (dj == 0) ? w0 : ((dj == 1) ? w1 : w2);
            float xc = (dj == 0) ? w1 : ((dj == 1) ? w2 : w3);
            o0 += xa * t0[dj * 3 + di];
            o1 += xc * t1[dj * 3 + di];
        }
    }
    float2 ov; ov.x = o0; ov.y = o1;
    *(float2*)(out + (size_t)b * Td * HWc + pix) = ov;
}

// ---------------------------------------------------------------------------
// Kernel 2: one scan-body iteration = 6 fused stencil steps.
// Thread t owns column c = t%76, rows rs..rs+7 (rs = 1 + 8*(t/76)); its 40
// fp16 T coefs live in 40 VGPRs; x ping-pongs in LDS with a streaming 3x3
// window. Sigmoid at even sub-steps. Region ring never written (contamination
// <=1 px/step, halo 6 protects the 64x64 core). sB: ring-only zero (interior
// is fully rewritten each step before being read).
// ---------------------------------------------------------------------------
__global__ __launch_bounds__(NTHR, 6)
void fused6_vstrip_kernel(const float* __restrict__ xin,   // out slot t-1 base
                          const __half2* __restrict__ T,
                          float* __restrict__ xout) {      // out slot t base
    __shared__ float sA[RS * LP];
    __shared__ float sB[RS * LP];

    int tile = blockIdx.x;          // 512 = 8 batches * 8x8 tiles
    int b   = tile >> 6;
    int trr = (tile >> 3) & 7;
    int tcc = tile & 7;
    int ri = trr * TS - H6;
    int rj = tcc * TS - H6;

    const float* xb = xin + (size_t)b * Td * HWc;
    const __half2* Tb = T + (size_t)b * 5 * HWc;
    int tid = threadIdx.x;

    // Stage sA (zeros outside image).
    for (int idx = tid; idx < RS * RS; idx += NTHR) {
        int r = idx / RS, c = idx - r * RS;
        int gi = ri + r, gj = rj + c;
        float v = 0.0f;
        if ((unsigned)gi < (unsigned)Hd && (unsigned)gj < (unsigned)Wd)
            v = xb[gi * Wd + gj];
        sA[r * LP + c] = v;
    }
    // Zero only sB's ring (4*RS - 4 = 300 cells).
    for (int idx = tid; idx < 4 * RS; idx += NTHR) {
        int side = idx / RS, k = idx - side * RS;
        int r, c;
        if (side == 0)      { r = 0;      c = k; }
        else if (side == 1) { r = RS - 1; c = k; }
        else if (side == 2) { r = k;      c = 0; }
        else                { r = k;      c = RS - 1; }
        sB[r * LP + c] = 0.0f;
    }

    int g  = tid / RS;              // row group 0..9 valid
    int c  = tid - g * RS;          // column 0..75
    int rs = 1 + g * RPG;           // first owned row
    bool colint = (c >= 1) && (c <= RS - 2);
    bool active = (g < NG) && colint;
    int  gj     = rj + c;
    bool colin  = (unsigned)gj < (unsigned)Wd;

    // T coefficients: 5 half2 per owned row.
    __half2 treg[RPG][5];
    #pragma unroll
    for (int jj = 0; jj < RPG; ++jj) {
        int r  = rs + jj;
        int gi = ri + r;
        bool ok = active && (r <= RS - 2) && ((unsigned)gi < (unsigned)Hd) && colin;
        #pragma unroll
        for (int q = 0; q < 5; ++q)
            treg[jj][q] = ok ? Tb[(size_t)q * HWc + gi * Wd + gj]
                             : __floats2half2_rn(0.0f, 0.0f);
    }
    __syncthreads();

    float* cur = sA;
    float* nxt = sB;

    #pragma unroll
    for (int s = 1; s <= 6; ++s) {
        if (active) {
            float w00 = cur[(rs - 1) * LP + c - 1];
            float w01 = cur[(rs - 1) * LP + c];
            float w02 = cur[(rs - 1) * LP + c + 1];
            float w10 = cur[rs * LP + c - 1];
            float w11 = cur[rs * LP + c];
            float w12 = cur[rs * LP + c + 1];
            #pragma unroll
            for (int jj = 0; jj < RPG; ++jj) {
                int r  = rs + jj;
                int r2 = (r + 1 <= RS - 1) ? (r + 1) : (RS - 1);  // clamp (g=9 tail)
                float w20 = cur[r2 * LP + c - 1];
                float w21 = cur[r2 * LP + c];
                float w22 = cur[r2 * LP + c + 1];

                float2 p0 = __half22float2(treg[jj][0]);  // T0,T1
                float2 p1 = __half22float2(treg[jj][1]);  // T2,T3
                float2 p2 = __half22float2(treg[jj][2]);  // T4,T5
                float2 p3 = __half22float2(treg[jj][3]);  // T6,T7
                float2 p4 = __half22float2(treg[jj][4]);  // T8,T9

                // k = dj*3+di multiplies x[r+di-1][c+dj-1]
                float a = p4.y
                        + w00 * p0.x + w10 * p0.y + w20 * p1.x
                        + w01 * p1.y + w11 * p2.x + w21 * p2.y
                        + w02 * p3.x + w12 * p3.y + w22 * p4.x;
                if ((s & 1) == 0) a = 1.0f / (1.0f + __expf(-a));

                int gi = ri + r;
                bool rowok = (r <= RS - 2);
                bool inimg = ((unsigned)gi < (unsigned)Hd) && colin;
                if (rowok) nxt[r * LP + c] = inimg ? a : 0.0f;

                w00 = w10; w01 = w11; w02 = w12;
                w10 = w20; w11 = w21; w12 = w22;
            }
        }
        __syncthreads();
        float* tmp = cur; cur = nxt; nxt = tmp;
    }

    // After 6 swaps the result is back in sA (== cur). Write 64x64 core.
    float* ob = xout + (size_t)b * Td * HWc;
    for (int idx = tid; idx < TS * TS; idx += NTHR) {
        int rr = idx >> 6, cc = idx & 63;
        ob[(ri + H6 + rr) * Wd + (rj + H6 + cc)] = cur[(H6 + rr) * LP + (H6 + cc)];
    }
}

// ---------------------------------------------------------------------------
// Workspace: T only (B*5*H*W half2 = 40 MB).
// ---------------------------------------------------------------------------
extern "C" void kernel_launch(void* const* d_in, const int* in_sizes, int n_in,
                              void* d_out, int out_size, void* d_ws, size_t ws_size,
                              hipStream_t stream) {
    const float* x  = (const float*)d_in[0];
    const float* Wu = (const float*)d_in[1];
    const float* bu = (const float*)d_in[2];
    float* out = (float*)d_out;
    __half2* T = (__half2*)d_ws;

    conv_step0_kernel<<<2048, CTHR, 0, stream>>>(x, Wu, bu, T, out);

    for (int t = 1; t < Td; ++t)
        fused6_vstrip_kernel<<<512, NTHR, 0, stream>>>(out + (size_t)(t - 1) * HWc, T,
                                                       out + (size_t)t * HWc);
}